// Round 17
// baseline (225.039 us; speedup 1.0000x reference)
//
#include <hip/hip_runtime.h>
#include <hip/hip_bf16.h>

// Node_EncodingBlock on MI355X. Inputs fp32, output fp32.
// R17: 3-kernel chain. R16 proved coop grid.sync is catastrophic (177us);
// instead the two k_red launches are folded into their producers via the
// last-block TICKET pattern: every block stores partials, __threadfence(),
// thread0 atomicAdd(ticket); the block drawing old==499 reduces all partials
// (~1.5us, coalesced) and resets the ticket (self-restoring; first-call 0xAA
// poison cleared by CAS-to-zero guard; deterministic every call).
// U/C0 computed by k_ffn block 0. Phase bodies = R16-validated device fns.

#define BN_EPS 1e-5f
// ws float offsets
#define WS_X1    256000     // [2000][128]
#define WS_X2    512000     // [2000][128]
#define WS_SUM1  768000     // [128]; SQ1 contiguous at +128
#define WS_SQ1   768128
#define WS_SUM2  768256     // [128]; SQ2 contiguous at +128
#define WS_SQ2   768384
#define WS_UV    768512
#define WS_C0V   768640
#define WS_TK1   768800     // ticket counters (unsigned)
#define WS_TK2   768804
#define BN1P     770000     // [500][256]
#define BN2P     900000     // [500][256]

struct P {
  const float *cost, *rnd, *dem, *Wv, *mix1w, *mix1b, *mix2w, *mix2b, *Wo, *bo;
  const float *W1, *b1, *g1, *bb1, *W2, *b2, *Wn, *Wd, *bd, *bnn, *g2, *bb2;
  float *out, *ws;
};

// 2-row GEMM micro-step (attn phase D / final)
#define GB8_R2(WPTR, LDW, KIDX, ACT2D, ACC)                             \
  {                                                                     \
    float4 w[8];                                                        \
    _Pragma("unroll")                                                   \
    for (int u = 0; u < 8; ++u)                                         \
      w[u] = *(const float4*)((WPTR) + (size_t)((KIDX) + u) * (LDW));   \
    _Pragma("unroll")                                                   \
    for (int u = 0; u < 8; ++u) {                                       \
      _Pragma("unroll")                                                 \
      for (int r = 0; r < 2; ++r) {                                     \
        float a = ACT2D[r][u];                                          \
        ACC[r][0] = fmaf(a, w[u].x, ACC[r][0]);                         \
        ACC[r][1] = fmaf(a, w[u].y, ACC[r][1]);                         \
        ACC[r][2] = fmaf(a, w[u].z, ACC[r][2]);                         \
        ACC[r][3] = fmaf(a, w[u].w, ACC[r][3]);                         \
      }                                                                 \
    }                                                                   \
  }

#define LD_AV2(SRC_ROW0, SRC_ROW1, KIDX, ACT2D)                         \
  {                                                                     \
    float4 x0 = *(const float4*)&(SRC_ROW0)[(KIDX)];                    \
    float4 y0 = *(const float4*)&(SRC_ROW0)[(KIDX) + 4];                \
    float4 x1 = *(const float4*)&(SRC_ROW1)[(KIDX)];                    \
    float4 y1 = *(const float4*)&(SRC_ROW1)[(KIDX) + 4];                \
    ACT2D[0][0]=x0.x; ACT2D[0][1]=x0.y; ACT2D[0][2]=x0.z; ACT2D[0][3]=x0.w; \
    ACT2D[0][4]=y0.x; ACT2D[0][5]=y0.y; ACT2D[0][6]=y0.z; ACT2D[0][7]=y0.w; \
    ACT2D[1][0]=x1.x; ACT2D[1][1]=x1.y; ACT2D[1][2]=x1.z; ACT2D[1][3]=x1.w; \
    ACT2D[1][4]=y1.x; ACT2D[1][5]=y1.y; ACT2D[1][6]=y1.z; ACT2D[1][7]=y1.w; \
  }

// 4-row x 4-col x 4-k batch: 4 independent float4 weight loads, 64 FMAs.
#define GB4_R4(WPTR, LDW, K0, SRC2D, ACC)                               \
  {                                                                     \
    float4 w[4];                                                        \
    _Pragma("unroll")                                                   \
    for (int u = 0; u < 4; ++u)                                         \
      w[u] = *(const float4*)((WPTR) + (size_t)((K0) + u) * (LDW));     \
    float av[4][4];                                                     \
    _Pragma("unroll")                                                   \
    for (int r = 0; r < 4; ++r) {                                       \
      float4 x = *(const float4*)&SRC2D[r][(K0)];                       \
      av[r][0] = x.x; av[r][1] = x.y; av[r][2] = x.z; av[r][3] = x.w;   \
    }                                                                   \
    _Pragma("unroll")                                                   \
    for (int u = 0; u < 4; ++u) {                                       \
      _Pragma("unroll")                                                 \
      for (int r = 0; r < 4; ++r) {                                     \
        ACC[r][0] = fmaf(av[r][u], w[u].x, ACC[r][0]);                  \
        ACC[r][1] = fmaf(av[r][u], w[u].y, ACC[r][1]);                  \
        ACC[r][2] = fmaf(av[r][u], w[u].z, ACC[r][2]);                  \
        ACC[r][3] = fmaf(av[r][u], w[u].w, ACC[r][3]);                  \
      }                                                                 \
    }                                                                   \
  }

struct SmA {
  float scost[4][512];
  float2 lut[2048];
  float aw[32][132];
  float soc[4][132];
  float sP[8][512];          // also traw scratch
  float svr[128];
  float mu[8][16], mr[8][16], mA[8], mB[8];
  int   sperm[128];
  float sS[512], sQ[512];
};
struct SmF {
  float o1[4][128];
  float sY[4][512];
  float sP[4][4][512];       // GEMM2 view [16][4][128]
  float sS[512], sQ[512];
};
struct SmC {
  float o3[4][132];
  float sP[8][4][128];
};

// ---- ticket: returns true for the LAST block to finish (thread-uniform) ---
__device__ __forceinline__ bool ticket_last(float* ws, int tkofs, int nblocks,
                                            int* shFlag) {
  __threadfence();                       // partials visible device-wide
  __syncthreads();
  unsigned* tk = (unsigned*)(ws + tkofs);
  if (threadIdx.x == 0) {
    unsigned cur = *(volatile unsigned*)tk;
    if (cur > (unsigned)nblocks) atomicCAS(tk, cur, 0u);   // clear 0xAA poison
    unsigned old = atomicAdd(tk, 1u);
    int last = (old == (unsigned)(nblocks - 1));
    if (last) atomicExch(tk, 0u);        // self-restore for next call
    *shFlag = last;
  }
  __syncthreads();
  return *shFlag != 0;
}

// ---- in-kernel reduce: [500][256] partials -> 256 floats at dst -----------
__device__ __forceinline__ void reduce_partials(float* ws, int src, int dst,
                                                float* stage) {
  __threadfence();                       // acquire: see all partials
  const int t = threadIdx.x;
  const int col = t & 255, half = t >> 8;
  float s = 0.f;
#pragma unroll 5
  for (int j = half * 250; j < half * 250 + 250; ++j)
    s += ws[src + j * 256 + col];
  stage[t] = s;
  __syncthreads();
  if (t < 256) ws[dst + t] = stage[t] + stage[t + 256];
}

// ---- attn phase: attention + multi_head_combine + BN1 partials ------------
__device__ __forceinline__ void attn_phase(const P& p, int blk, SmA& a) {
  const int t = threadIdx.x;
  const int lane = t & 63;
  const int row0 = blk * 4;
  const int b = blk / 125;
  float* ws = p.ws;
  {
    int rr = t >> 7, i4 = t & 127;
    *(float4*)&a.scost[rr][i4 * 4] = (i4 < 125)
        ? *(const float4*)(p.cost + (size_t)(row0 + rr) * 500 + i4 * 4)
        : float4{0.f, 0.f, 0.f, 0.f};
  }
  if (t < 128) a.svr[t] = p.rnd[b * 128 + t];
  __syncthreads();
  if (t < 128) {
    float vt = a.svr[t];
    int rank = 0;
    for (int j = 0; j < 128; ++j) {
      float vj = a.svr[j];
      rank += (vj < vt) || (vj == vt && j < t);
    }
    a.sperm[rank] = t;
    // abs-form MLP params: g(c) = A c + B + sum u_s |c - r_s|
    int h = t >> 4, s = t & 15;
    float w1  = p.mix1w[h * 32 + 16 + s];
    float b1v = p.mix1b[h * 16 + s];
    float w2  = p.mix2w[h * 16 + s];
    bool tiny = fabsf(w1) < 1e-20f;
    float us = tiny ? 0.f : 0.5f * w2 * fabsf(w1);
    float rs = tiny ? 0.f : -b1v / w1;
    float Ap = 0.5f * w2 * w1;
    float Bp = 0.5f * w2 * b1v + (tiny ? 0.5f * w2 * fabsf(b1v) : 0.f);
    a.mu[h][s] = us; a.mr[h][s] = rs;
#pragma unroll
    for (int off = 1; off < 16; off <<= 1) {
      Ap += __shfl_xor(Ap, off);
      Bp += __shfl_xor(Bp, off);
    }
    if (s == 0) { a.mA[h] = Ap; a.mB[h] = Bp + p.mix2b[h]; }
  }
  __syncthreads();
  float* traw = &a.sP[0][0];
  if (t < 257) {
    float x = (float)t * (1.f / 255.f);
    for (int h = 0; h < 8; ++h) {
      float g = fmaf(x, a.mA[h], a.mB[h]);
#pragma unroll
      for (int s = 0; s < 16; ++s)
        g = fmaf(fabsf(x - a.mr[h][s]), a.mu[h][s], g);
      traw[h * 257 + t] = __expf(g);
    }
  }
  __syncthreads();
#pragma unroll
  for (int pq = 0; pq < 4; ++pq) {
    int e = t + pq * 512;
    int h = e >> 8, i = e & 255;
    float av = traw[h * 257 + i];
    a.lut[e] = float2{av, traw[h * 257 + i + 1] - av};
  }
  __syncthreads();
  // phase B: wave (row, head-half): LUT scores -> aggregated softmax weights
  {
    const int wid = t >> 6;
    const int r  = wid & 3;
    const int h0 = (wid >> 2) * 4;
    float cv8[8];
#pragma unroll
    for (int ii = 0; ii < 8; ++ii) cv8[ii] = a.scost[r][ii * 64 + lane];
    for (int h = h0; h < h0 + 4; ++h) {
      const float2* lh = &a.lut[h * 256];
      float wsum = 0.f, a0 = 0.f, a1 = 0.f;
#pragma unroll
      for (int ii = 0; ii < 8; ++ii) {
        float u = cv8[ii] * 255.f;
        int i = (int)u;
        float f = u - (float)i;
        float2 td = lh[i];
        float e = fmaf(td.y, f, td.x);
        if (ii == 7 && lane >= 52) e = 0.f;   // mask m >= 500
        wsum += e;
        if (ii & 1) a1 += e; else a0 += e;
      }
#pragma unroll
      for (int off = 32; off; off >>= 1) wsum += __shfl_xor(wsum, off);
      float inv = 1.f / wsum;
      a.aw[r * 8 + h][lane]      = a0 * inv;
      a.aw[r * 8 + h][64 + lane] = a1 * inv;
    }
  }
  __syncthreads();
  // phase C: oc[r][c] = sum_j aw[r*8+(c>>4)][j] * Wv[perm[j]][c]; j-split 4
  {
    const int c  = t & 127;
    const int jh = t >> 7;
    const int h  = c >> 4;
    float acc4[4] = {0.f, 0.f, 0.f, 0.f};
    for (int jb = jh * 32; jb < jh * 32 + 32; jb += 8) {
      int rows[8];
#pragma unroll
      for (int u = 0; u < 8; ++u) rows[u] = a.sperm[jb + u];
      float wv8[8];
#pragma unroll
      for (int u = 0; u < 8; ++u) wv8[u] = p.Wv[(size_t)rows[u] * 128 + c];
#pragma unroll
      for (int r = 0; r < 4; ++r) {
        float4 aa = *(const float4*)&a.aw[r * 8 + h][jb];
        float4 ab = *(const float4*)&a.aw[r * 8 + h][jb + 4];
        acc4[r] = fmaf(aa.x, wv8[0], acc4[r]);
        acc4[r] = fmaf(aa.y, wv8[1], acc4[r]);
        acc4[r] = fmaf(aa.z, wv8[2], acc4[r]);
        acc4[r] = fmaf(aa.w, wv8[3], acc4[r]);
        acc4[r] = fmaf(ab.x, wv8[4], acc4[r]);
        acc4[r] = fmaf(ab.y, wv8[5], acc4[r]);
        acc4[r] = fmaf(ab.z, wv8[6], acc4[r]);
        acc4[r] = fmaf(ab.w, wv8[7], acc4[r]);
      }
    }
#pragma unroll
    for (int r = 0; r < 4; ++r) a.sP[jh][r * 128 + c] = acc4[r];
  }
  __syncthreads();
  {
    int r = t >> 7, c = t & 127;
    a.soc[r][c] = a.sP[0][r * 128 + c] + a.sP[1][r * 128 + c] +
                  a.sP[2][r * 128 + c] + a.sP[3][r * 128 + c];
  }
  __syncthreads();
  // phase D: X1 = soc @ Wo + bo; k-split 8 x row-half 2
  {
    const int cg  = (t & 31) * 4;
    const int seg = (t >> 5) & 7;
    const int rh  = t >> 8;
    const int k0  = seg * 16;
    float acc[2][4] = {};
    float av[2][8];
#pragma unroll
    for (int kb = 0; kb < 16; kb += 8) {
      LD_AV2(a.soc[rh * 2], a.soc[rh * 2 + 1], k0 + kb, av);
      GB8_R2(p.Wo + cg, 128, k0 + kb, av, acc);
    }
#pragma unroll
    for (int r = 0; r < 2; ++r)
      *(float4*)&a.sP[seg][(rh * 2 + r) * 128 + cg] = *(float4*)acc[r];
  }
  __syncthreads();
  {
    int r = t >> 7, col = t & 127;
    float x = p.bo[col];
#pragma unroll
    for (int sg = 0; sg < 8; ++sg) x += a.sP[sg][r * 128 + col];
    ws[WS_X1 + (size_t)(row0 + r) * 128 + col] = x;
    a.sS[t] = x; a.sQ[t] = x * x;
  }
  __syncthreads();
  if (t < 128) {
    ws[BN1P + blk * 256 + t] =
        a.sS[t] + a.sS[t+128] + a.sS[t+256] + a.sS[t+384];
    ws[BN1P + blk * 256 + 128 + t] =
        a.sQ[t] + a.sQ[t+128] + a.sQ[t+256] + a.sQ[t+384];
  }
}

// ---- U/C0 (k_ffn block 0) -------------------------------------------------
__device__ __forceinline__ void uc0_phase(const P& p, float* stage) {
  const int t = threadIdx.x;
  const int c = t & 127, g = t >> 7;
  float u = 0.f, cc = 0.f;
#pragma unroll 8
  for (int e = g * 32; e < g * 32 + 32; ++e) {
    float wn = p.Wn[(size_t)(128 + e) * 128 + c];
    u  = fmaf(p.Wd[e], wn, u);
    cc = fmaf(p.bd[e], wn, cc);
  }
  __syncthreads();
  stage[t] = u;
  __syncthreads();
  if (t < 128)
    p.ws[WS_UV + t] = stage[t] + stage[t+128] + stage[t+256] + stage[t+384];
  __syncthreads();
  stage[t] = cc;
  __syncthreads();
  if (t < 128)
    p.ws[WS_C0V + t] = stage[t] + stage[t+128] + stage[t+256] + stage[t+384] +
                       p.bnn[t];
}

// ---- ffn phase: BN1 -> FFN -> X2 + BN2 partials ---------------------------
__device__ __forceinline__ void ffn_phase(const P& p, int blk, SmF& f) {
  const int t = threadIdx.x;
  const int row0 = blk * 4;
  float* ws = p.ws;
  const int c0 = t & 127;
  float m1 = ws[WS_SUM1 + c0] * 5e-4f;
  float v1 = ws[WS_SQ1 + c0] * 5e-4f - m1 * m1;
  float scv = p.g1[c0] * rsqrtf(v1 + BN_EPS);
  float shv = p.bb1[c0] - m1 * scv;
  {
    int r = t >> 7;
    f.o1[r][c0] = ws[WS_X1 + (size_t)(row0 + r) * 128 + c0] * scv + shv;
  }
  __syncthreads();
  // GEMM1 (128->512): cg(128 x 4cols) x kseg(4 x 32k)
  {
    const int cg   = (t & 127) * 4;
    const int kseg = t >> 7;
    const int kb0  = kseg * 32;
    float acc[4][4] = {};
#pragma unroll
    for (int kb = 0; kb < 32; kb += 4)
      GB4_R4(p.W1 + cg, 512, kb0 + kb, f.o1, acc);
#pragma unroll
    for (int r = 0; r < 4; ++r)
      *(float4*)&f.sP[kseg][r][cg] = *(float4*)acc[r];
  }
  __syncthreads();
#pragma unroll
  for (int i = 0; i < 4; ++i) {
    int idx = t + i * 512;
    int r = idx >> 9, c = idx & 511;
    float x = f.sP[0][r][c] + f.sP[1][r][c] + f.sP[2][r][c] + f.sP[3][r][c];
    f.sY[r][c] = fmaxf(x + p.b1[c], 0.f);
  }
  __syncthreads();
  // GEMM2 (512->128): cg(32 x 4cols) x kseg(16 x 32k)
  float* p2 = &f.sP[0][0][0];          // [16][4][128] view
  {
    const int cg   = (t & 31) * 4;
    const int kseg = t >> 5;
    const int kb0  = kseg * 32;
    float acc[4][4] = {};
#pragma unroll
    for (int kb = 0; kb < 32; kb += 4)
      GB4_R4(p.W2 + cg, 128, kb0 + kb, f.sY, acc);
#pragma unroll
    for (int r = 0; r < 4; ++r)
      *(float4*)(p2 + (size_t)(kseg * 4 + r) * 128 + cg) = *(float4*)acc[r];
  }
  __syncthreads();
  {
    int r = t >> 7, c = t & 127;
    float x = p.b2[c] + f.o1[r][c];
#pragma unroll
    for (int sg = 0; sg < 16; ++sg) x += p2[(size_t)(sg * 4 + r) * 128 + c];
    ws[WS_X2 + (size_t)(row0 + r) * 128 + c] = x;
    f.sS[t] = x; f.sQ[t] = x * x;
  }
  __syncthreads();
  if (t < 128) {
    ws[BN2P + blk * 256 + t] =
        f.sS[t] + f.sS[t+128] + f.sS[t+256] + f.sS[t+384];
    ws[BN2P + blk * 256 + 128 + t] =
        f.sQ[t] + f.sQ[t+128] + f.sQ[t+256] + f.sQ[t+384];
  }
}

// ---- final phase: BN2 -> out3 @ Wn_top + demand*U + C0 -> out -------------
__device__ __forceinline__ void final_phase(const P& p, int blk, SmC& c) {
  const int t = threadIdx.x;
  const int row0 = blk * 4;
  float* ws = p.ws;
  const int c0 = t & 127;
  float m2 = ws[WS_SUM2 + c0] * 5e-4f;
  float v2 = ws[WS_SQ2 + c0] * 5e-4f - m2 * m2;
  float scv = p.g2[c0] * rsqrtf(v2 + BN_EPS);
  float shv = p.bb2[c0] - m2 * scv;
  {
    int r = t >> 7;
    c.o3[r][c0] = ws[WS_X2 + (size_t)(row0 + r) * 128 + c0] * scv + shv;
  }
  __syncthreads();
  {
    const int cg  = (t & 31) * 4;
    const int seg = (t >> 5) & 7;
    const int rh  = t >> 8;
    const int k0  = seg * 16;
    float acc[2][4] = {};
    float av[2][8];
#pragma unroll
    for (int kb = 0; kb < 16; kb += 8) {
      LD_AV2(c.o3[rh * 2], c.o3[rh * 2 + 1], k0 + kb, av);
      GB8_R2(p.Wn + cg, 128, k0 + kb, av, acc);
    }
#pragma unroll
    for (int r = 0; r < 2; ++r)
      *(float4*)&c.sP[seg][rh * 2 + r][cg] = *(float4*)acc[r];
  }
  __syncthreads();
  {
    int r = t >> 7;
    float x = ws[WS_C0V + c0] + p.dem[row0 + r] * ws[WS_UV + c0];
#pragma unroll
    for (int sg = 0; sg < 8; ++sg) x += c.sP[sg][r][c0];
    p.out[(size_t)(row0 + r) * 128 + c0] = x;
  }
}

// ---- kernels --------------------------------------------------------------
__global__ __launch_bounds__(512, 4) void k_attn3(P p) {
  __shared__ SmA a;
  __shared__ int shLast;
  attn_phase(p, blockIdx.x, a);
  if (ticket_last(p.ws, WS_TK1, 500, &shLast))
    reduce_partials(p.ws, BN1P, WS_SUM1, a.sS);
}

__global__ __launch_bounds__(512, 2) void k_ffn3(P p) {
  __shared__ SmF f;
  __shared__ int shLast;
  ffn_phase(p, blockIdx.x, f);
  if (blockIdx.x == 0) uc0_phase(p, f.sS);
  if (ticket_last(p.ws, WS_TK2, 500, &shLast))
    reduce_partials(p.ws, BN2P, WS_SUM2, f.sQ);
}

__global__ __launch_bounds__(512, 4) void k_final3(P p) {
  __shared__ SmC c;
  final_phase(p, blockIdx.x, c);
}

extern "C" void kernel_launch(void* const* d_in, const int* in_sizes, int n_in,
                              void* d_out, int out_size, void* d_ws, size_t ws_size,
                              hipStream_t stream) {
  P p;
  p.cost  = (const float*)d_in[0];
  p.dem   = (const float*)d_in[1];
  p.rnd   = (const float*)d_in[2];
  // d_in[3] Wq, d_in[4] Wk unused (q == 0)
  p.Wv    = (const float*)d_in[5];
  p.mix1w = (const float*)d_in[6];
  p.mix1b = (const float*)d_in[7];
  p.mix2w = (const float*)d_in[8];
  p.mix2b = (const float*)d_in[9];
  p.Wo    = (const float*)d_in[10];
  p.bo    = (const float*)d_in[11];
  p.W1    = (const float*)d_in[12];
  p.b1    = (const float*)d_in[13];
  p.W2    = (const float*)d_in[14];
  p.b2    = (const float*)d_in[15];
  p.g1    = (const float*)d_in[16];
  p.bb1   = (const float*)d_in[17];
  p.g2    = (const float*)d_in[18];
  p.bb2   = (const float*)d_in[19];
  p.Wd    = (const float*)d_in[20];
  p.bd    = (const float*)d_in[21];
  p.Wn    = (const float*)d_in[22];
  p.bnn   = (const float*)d_in[23];
  p.out   = (float*)d_out;
  p.ws    = (float*)d_ws;

  hipLaunchKernelGGL(k_attn3,  dim3(500), dim3(512), 0, stream, p);
  hipLaunchKernelGGL(k_ffn3,   dim3(500), dim3(512), 0, stream, p);
  hipLaunchKernelGGL(k_final3, dim3(500), dim3(512), 0, stream, p);
}

// Round 18
// 50.643 us; speedup vs baseline: 4.4437x; 4.4437x over previous
//
#include <hip/hip_runtime.h>
#include <hip/hip_bf16.h>

// Node_EncodingBlock on MI355X. Inputs fp32, output fp32.
// R18: ticket/coop/memset all rejected (threadfence=100us, grid.sync=130us,
// async-fill=41us) -> 5-kernel chain is structural. One lever: attn 2->3
// blocks/CU via surgical LDS diet (65.6K -> 45.7K), keeping ALL validated
// structure: raw 8x257 LUT (two adjacent gathers, no packed float2), phase D
// re-tiled to [4][512] partials (4 ksegs x 2-col float2 groups), sS/sQ
// aliased into aw (dead after phase C). Other kernels identical to R14.

#define BN_EPS 1e-5f
// ws float offsets
#define WS_X1    256000     // [2000][128]
#define WS_X2    512000     // [2000][128]
#define WS_SUM1  768000
#define WS_SQ1   768128
#define WS_SUM2  768256
#define WS_SQ2   768384
#define WS_UV    768512
#define WS_C0V   768640
#define BN1P     770000     // [500][256]
#define BN2P     900000     // [500][256]

// 2-row GEMM micro-step (final)
#define GB8_R2(WPTR, LDW, KIDX, ACT2D, ACC)                             \
  {                                                                     \
    float4 w[8];                                                        \
    _Pragma("unroll")                                                   \
    for (int u = 0; u < 8; ++u)                                         \
      w[u] = *(const float4*)((WPTR) + (size_t)((KIDX) + u) * (LDW));   \
    _Pragma("unroll")                                                   \
    for (int u = 0; u < 8; ++u) {                                       \
      _Pragma("unroll")                                                 \
      for (int r = 0; r < 2; ++r) {                                     \
        float a = ACT2D[r][u];                                          \
        ACC[r][0] = fmaf(a, w[u].x, ACC[r][0]);                         \
        ACC[r][1] = fmaf(a, w[u].y, ACC[r][1]);                         \
        ACC[r][2] = fmaf(a, w[u].z, ACC[r][2]);                         \
        ACC[r][3] = fmaf(a, w[u].w, ACC[r][3]);                         \
      }                                                                 \
    }                                                                   \
  }

#define LD_AV2(SRC_ROW0, SRC_ROW1, KIDX, ACT2D)                         \
  {                                                                     \
    float4 x0 = *(const float4*)&(SRC_ROW0)[(KIDX)];                    \
    float4 y0 = *(const float4*)&(SRC_ROW0)[(KIDX) + 4];                \
    float4 x1 = *(const float4*)&(SRC_ROW1)[(KIDX)];                    \
    float4 y1 = *(const float4*)&(SRC_ROW1)[(KIDX) + 4];                \
    ACT2D[0][0]=x0.x; ACT2D[0][1]=x0.y; ACT2D[0][2]=x0.z; ACT2D[0][3]=x0.w; \
    ACT2D[0][4]=y0.x; ACT2D[0][5]=y0.y; ACT2D[0][6]=y0.z; ACT2D[0][7]=y0.w; \
    ACT2D[1][0]=x1.x; ACT2D[1][1]=x1.y; ACT2D[1][2]=x1.z; ACT2D[1][3]=x1.w; \
    ACT2D[1][4]=y1.x; ACT2D[1][5]=y1.y; ACT2D[1][6]=y1.z; ACT2D[1][7]=y1.w; \
  }

// 4-row x 4-col x 4-k batch: 4 independent float4 weight loads, 64 FMAs.
#define GB4_R4(WPTR, LDW, K0, SRC2D, ACC)                               \
  {                                                                     \
    float4 w[4];                                                        \
    _Pragma("unroll")                                                   \
    for (int u = 0; u < 4; ++u)                                         \
      w[u] = *(const float4*)((WPTR) + (size_t)((K0) + u) * (LDW));     \
    float av[4][4];                                                     \
    _Pragma("unroll")                                                   \
    for (int r = 0; r < 4; ++r) {                                       \
      float4 x = *(const float4*)&SRC2D[r][(K0)];                       \
      av[r][0] = x.x; av[r][1] = x.y; av[r][2] = x.z; av[r][3] = x.w;   \
    }                                                                   \
    _Pragma("unroll")                                                   \
    for (int u = 0; u < 4; ++u) {                                       \
      _Pragma("unroll")                                                 \
      for (int r = 0; r < 4; ++r) {                                     \
        ACC[r][0] = fmaf(av[r][u], w[u].x, ACC[r][0]);                  \
        ACC[r][1] = fmaf(av[r][u], w[u].y, ACC[r][1]);                  \
        ACC[r][2] = fmaf(av[r][u], w[u].z, ACC[r][2]);                  \
        ACC[r][3] = fmaf(av[r][u], w[u].w, ACC[r][3]);                  \
      }                                                                 \
    }                                                                   \
  }

// ---- kA: attention + multi_head_combine + BN1 partials --------------------
// 500 blocks x 512 thr, 4 rows/block. 45.7KB LDS -> 3 blocks/CU.
__global__ __launch_bounds__(512, 6) void k_attn(const float* __restrict__ cost,
                                                 const float* __restrict__ rnd,
                                                 const float* __restrict__ Wv,
                                                 const float* __restrict__ mix1w,
                                                 const float* __restrict__ mix1b,
                                                 const float* __restrict__ mix2w,
                                                 const float* __restrict__ mix2b,
                                                 const float* __restrict__ Wo,
                                                 const float* __restrict__ bo,
                                                 float* __restrict__ ws) {
  __shared__ float scost[4][512];      // 8 KB
  __shared__ float lut[8 * 257];       // 8.2 KB raw exp table
  __shared__ float aw[32][132];        // 16.9 KB; rows 16B-aligned; sS/sQ alias
  __shared__ float soc[4][132];        // 2.1 KB
  __shared__ float sP[4][512];         // 8 KB (phase C partials AND phase D)
  __shared__ float svr[128];
  __shared__ float mu[8][16], mr[8][16], mA[8], mB[8];
  __shared__ int   sperm[128];
  const int t = threadIdx.x;
  const int lane = t & 63;
  const int blk = blockIdx.x;
  const int row0 = blk * 4;
  const int b = blk / 125;

  {
    int rr = t >> 7, i4 = t & 127;
    *(float4*)&scost[rr][i4 * 4] = (i4 < 125)
        ? *(const float4*)(cost + (size_t)(row0 + rr) * 500 + i4 * 4)
        : float4{0.f, 0.f, 0.f, 0.f};
  }
  if (t < 128) svr[t] = rnd[b * 128 + t];
  __syncthreads();
  if (t < 128) {
    float vt = svr[t];
    int rank = 0;
    for (int j = 0; j < 128; ++j) {
      float vj = svr[j];
      rank += (vj < vt) || (vj == vt && j < t);
    }
    sperm[rank] = t;
    // abs-form MLP params: g(c) = A c + B + sum u_s |c - r_s|
    int h = t >> 4, s = t & 15;
    float w1  = mix1w[h * 32 + 16 + s];
    float b1v = mix1b[h * 16 + s];
    float w2  = mix2w[h * 16 + s];
    bool tiny = fabsf(w1) < 1e-20f;
    float us = tiny ? 0.f : 0.5f * w2 * fabsf(w1);
    float rs = tiny ? 0.f : -b1v / w1;
    float Ap = 0.5f * w2 * w1;
    float Bp = 0.5f * w2 * b1v + (tiny ? 0.5f * w2 * fabsf(b1v) : 0.f);
    mu[h][s] = us; mr[h][s] = rs;
#pragma unroll
    for (int off = 1; off < 16; off <<= 1) {
      Ap += __shfl_xor(Ap, off);
      Bp += __shfl_xor(Bp, off);
    }
    if (s == 0) { mA[h] = Ap; mB[h] = Bp + mix2b[h]; }
  }
  __syncthreads();
  // LUT: lut[h][i] = exp(g_h(i/255)), i in [0,256]
  if (t < 257) {
    float x = (float)t * (1.f / 255.f);
    for (int h = 0; h < 8; ++h) {
      float g = fmaf(x, mA[h], mB[h]);
#pragma unroll
      for (int s = 0; s < 16; ++s)
        g = fmaf(fabsf(x - mr[h][s]), mu[h][s], g);
      lut[h * 257 + t] = __expf(g);
    }
  }
  __syncthreads();
  // phase B: wave (row, head-half): 2-gather interp -> aggregated weights
  {
    const int wid = t >> 6;
    const int r  = wid & 3;
    const int h0 = (wid >> 2) * 4;
    float cv8[8];
#pragma unroll
    for (int ii = 0; ii < 8; ++ii) cv8[ii] = scost[r][ii * 64 + lane];
    for (int h = h0; h < h0 + 4; ++h) {
      const float* lT = &lut[h * 257];
      float wsum = 0.f, a0 = 0.f, a1 = 0.f;
#pragma unroll
      for (int ii = 0; ii < 8; ++ii) {
        float u = cv8[ii] * 255.f;      // cost in [0,1) -> u < 255
        int i = (int)u;
        float f = u - (float)i;
        float t0 = lT[i], t1 = lT[i + 1];
        float e = fmaf(t1 - t0, f, t0);
        if (ii == 7 && lane >= 52) e = 0.f;   // mask m >= 500
        wsum += e;
        if (ii & 1) a1 += e; else a0 += e;
      }
#pragma unroll
      for (int off = 32; off; off >>= 1) wsum += __shfl_xor(wsum, off);
      float inv = 1.f / wsum;
      aw[r * 8 + h][lane]      = a0 * inv;
      aw[r * 8 + h][64 + lane] = a1 * inv;
    }
  }
  __syncthreads();
  // phase C: oc[r][c] = sum_j aw[r*8+(c>>4)][j] * Wv[perm[j]][c]; j-split 4
  {
    const int c  = t & 127;
    const int jh = t >> 7;
    const int h  = c >> 4;
    float acc4[4] = {0.f, 0.f, 0.f, 0.f};
    for (int jb = jh * 32; jb < jh * 32 + 32; jb += 8) {
      int rows[8];
#pragma unroll
      for (int u = 0; u < 8; ++u) rows[u] = sperm[jb + u];
      float wv8[8];
#pragma unroll
      for (int u = 0; u < 8; ++u) wv8[u] = Wv[(size_t)rows[u] * 128 + c];
#pragma unroll
      for (int r = 0; r < 4; ++r) {
        float4 aa = *(const float4*)&aw[r * 8 + h][jb];
        float4 ab = *(const float4*)&aw[r * 8 + h][jb + 4];
        acc4[r] = fmaf(aa.x, wv8[0], acc4[r]);
        acc4[r] = fmaf(aa.y, wv8[1], acc4[r]);
        acc4[r] = fmaf(aa.z, wv8[2], acc4[r]);
        acc4[r] = fmaf(aa.w, wv8[3], acc4[r]);
        acc4[r] = fmaf(ab.x, wv8[4], acc4[r]);
        acc4[r] = fmaf(ab.y, wv8[5], acc4[r]);
        acc4[r] = fmaf(ab.z, wv8[6], acc4[r]);
        acc4[r] = fmaf(ab.w, wv8[7], acc4[r]);
      }
    }
#pragma unroll
    for (int r = 0; r < 4; ++r) sP[jh][r * 128 + c] = acc4[r];
  }
  __syncthreads();
  {
    int r = t >> 7, c = t & 127;
    soc[r][c] = sP[0][r * 128 + c] + sP[1][r * 128 + c] +
                sP[2][r * 128 + c] + sP[3][r * 128 + c];
  }
  __syncthreads();
  // phase D: X1 = soc @ Wo + bo; 4 ksegs x 2-col groups x 2 row-halves
  {
    const int cg2 = (t & 63) * 2;      // 64 col-groups of 2
    const int seg = (t >> 6) & 3;      // 4 k-segs of 32
    const int rh  = t >> 8;            // rows rh*2, rh*2+1
    const int k0  = seg * 32;
    float acc[2][2] = {};
#pragma unroll
    for (int kb = 0; kb < 32; kb += 8) {
      float2 w[8];
#pragma unroll
      for (int u = 0; u < 8; ++u)
        w[u] = *(const float2*)(Wo + (size_t)(k0 + kb + u) * 128 + cg2);
      float av[2][8];
      LD_AV2(soc[rh * 2], soc[rh * 2 + 1], k0 + kb, av);
#pragma unroll
      for (int u = 0; u < 8; ++u) {
#pragma unroll
        for (int r = 0; r < 2; ++r) {
          acc[r][0] = fmaf(av[r][u], w[u].x, acc[r][0]);
          acc[r][1] = fmaf(av[r][u], w[u].y, acc[r][1]);
        }
      }
    }
#pragma unroll
    for (int r = 0; r < 2; ++r)
      *(float2*)&sP[seg][(rh * 2 + r) * 128 + cg2] = float2{acc[r][0], acc[r][1]};
  }
  __syncthreads();
  {
    float* sS = &aw[0][0];             // aw dead after phase C
    float* sQ = sS + 512;
    int r = t >> 7, col = t & 127;
    float x = bo[col];
#pragma unroll
    for (int sg = 0; sg < 4; ++sg) x += sP[sg][r * 128 + col];
    ws[WS_X1 + (size_t)(row0 + r) * 128 + col] = x;
    sS[t] = x; sQ[t] = x * x;
    __syncthreads();
    if (t < 128) {
      ws[BN1P + blk * 256 + t]       = sS[t] + sS[t+128] + sS[t+256] + sS[t+384];
      ws[BN1P + blk * 256 + 128 + t] = sQ[t] + sQ[t+128] + sQ[t+256] + sQ[t+384];
    }
  }
}

// ---- k_red: 32 blocks reduce partials; block 32 (if present): U/C0 --------
__global__ __launch_bounds__(256) void k_red(const float* __restrict__ Wn,
                                             const float* __restrict__ Wd,
                                             const float* __restrict__ bd,
                                             const float* __restrict__ bnn,
                                             float* __restrict__ ws,
                                             int src, int nslots, int dst) {
  const int t = threadIdx.x;
  if (blockIdx.x < 32) {
    __shared__ float red[32][9];
    const int col = blockIdx.x * 8 + (t & 7);
    const int strip = t >> 3;          // 0..31
    float s = 0.f;
    for (int j = strip; j < nslots; j += 32) s += ws[src + j * 256 + col];
    red[strip][t & 7] = s;
    __syncthreads();
    if (t < 8) {
      float x = 0.f;
#pragma unroll
      for (int k = 0; k < 32; ++k) x += red[k][t];
      ws[dst + blockIdx.x * 8 + t] = x;
    }
  } else {
    __shared__ float ru[2][128], rc[2][128];
    const int c = t & 127, g = t >> 7;
    float u = 0.f, cc = 0.f;
#pragma unroll 8
    for (int e = g * 64; e < g * 64 + 64; ++e) {
      float wn = Wn[(size_t)(128 + e) * 128 + c];
      u  = fmaf(Wd[e], wn, u);
      cc = fmaf(bd[e], wn, cc);
    }
    ru[g][c] = u; rc[g][c] = cc;
    __syncthreads();
    if (t < 128) {
      ws[WS_UV + t]  = ru[0][t] + ru[1][t];
      ws[WS_C0V + t] = rc[0][t] + rc[1][t] + bnn[t];
    }
  }
}

// ---- kB: BN1 -> FFN -> X2 + BN2 partials (identical to R14) ---------------
__global__ __launch_bounds__(512, 2) void k_ffn(const float* __restrict__ W1,
                                                const float* __restrict__ b1,
                                                const float* __restrict__ g1,
                                                const float* __restrict__ bb1,
                                                const float* __restrict__ W2,
                                                const float* __restrict__ b2,
                                                float* __restrict__ ws) {
  __shared__ float o1[4][128];
  __shared__ float sY[4][512];
  __shared__ float sP[4][4][512];      // 32 KB; GEMM2 view [16][4][128]
  __shared__ float sS[512], sQ[512];
  const int t = threadIdx.x;
  const int blk = blockIdx.x;
  const int row0 = blk * 4;
  const int c0 = t & 127;
  float m1 = ws[WS_SUM1 + c0] * 5e-4f;
  float v1 = ws[WS_SQ1 + c0] * 5e-4f - m1 * m1;
  float scv = g1[c0] * rsqrtf(v1 + BN_EPS);
  float shv = bb1[c0] - m1 * scv;
  {
    int r = t >> 7;
    o1[r][c0] = ws[WS_X1 + (size_t)(row0 + r) * 128 + c0] * scv + shv;
  }
  __syncthreads();
  {
    const int cg   = (t & 127) * 4;
    const int kseg = t >> 7;
    const int kb0  = kseg * 32;
    float acc[4][4] = {};
#pragma unroll
    for (int kb = 0; kb < 32; kb += 4)
      GB4_R4(W1 + cg, 512, kb0 + kb, o1, acc);
#pragma unroll
    for (int r = 0; r < 4; ++r)
      *(float4*)&sP[kseg][r][cg] = *(float4*)acc[r];
  }
  __syncthreads();
#pragma unroll
  for (int i = 0; i < 4; ++i) {
    int idx = t + i * 512;
    int r = idx >> 9, c = idx & 511;
    float x = sP[0][r][c] + sP[1][r][c] + sP[2][r][c] + sP[3][r][c];
    sY[r][c] = fmaxf(x + b1[c], 0.f);
  }
  __syncthreads();
  float* p2 = &sP[0][0][0];            // [16][4][128] view
  {
    const int cg   = (t & 31) * 4;
    const int kseg = t >> 5;
    const int kb0  = kseg * 32;
    float acc[4][4] = {};
#pragma unroll
    for (int kb = 0; kb < 32; kb += 4)
      GB4_R4(W2 + cg, 128, kb0 + kb, sY, acc);
#pragma unroll
    for (int r = 0; r < 4; ++r)
      *(float4*)(p2 + (size_t)(kseg * 4 + r) * 128 + cg) = *(float4*)acc[r];
  }
  __syncthreads();
  {
    int r = t >> 7, c = t & 127;
    float x = b2[c] + o1[r][c];
#pragma unroll
    for (int sg = 0; sg < 16; ++sg) x += p2[(size_t)(sg * 4 + r) * 128 + c];
    ws[WS_X2 + (size_t)(row0 + r) * 128 + c] = x;
    sS[t] = x; sQ[t] = x * x;
  }
  __syncthreads();
  if (t < 128) {
    ws[BN2P + blk * 256 + t]       = sS[t] + sS[t+128] + sS[t+256] + sS[t+384];
    ws[BN2P + blk * 256 + 128 + t] = sQ[t] + sQ[t+128] + sQ[t+256] + sQ[t+384];
  }
}

// ---- kC: BN2 -> out3 @ Wn_top + demand*U + C0 -> out (identical to R14) ---
__global__ __launch_bounds__(512, 4) void k_final(const float* __restrict__ Wn,
                                                  const float* __restrict__ g2,
                                                  const float* __restrict__ bb2,
                                                  const float* __restrict__ dem,
                                                  float* __restrict__ outp,
                                                  float* __restrict__ ws) {
  __shared__ float o3[4][132];
  __shared__ float sP[8][4][128];
  const int t = threadIdx.x;
  const int blk = blockIdx.x;
  const int row0 = blk * 4;
  const int c0 = t & 127;
  float m2 = ws[WS_SUM2 + c0] * 5e-4f;
  float v2 = ws[WS_SQ2 + c0] * 5e-4f - m2 * m2;
  float scv = g2[c0] * rsqrtf(v2 + BN_EPS);
  float shv = bb2[c0] - m2 * scv;
  {
    int r = t >> 7;
    o3[r][c0] = ws[WS_X2 + (size_t)(row0 + r) * 128 + c0] * scv + shv;
  }
  __syncthreads();
  {
    const int cg  = (t & 31) * 4;
    const int seg = (t >> 5) & 7;
    const int rh  = t >> 8;
    const int k0  = seg * 16;
    float acc[2][4] = {};
    float av[2][8];
#pragma unroll
    for (int kb = 0; kb < 16; kb += 8) {
      LD_AV2(o3[rh * 2], o3[rh * 2 + 1], k0 + kb, av);
      GB8_R2(Wn + cg, 128, k0 + kb, av, acc);
    }
#pragma unroll
    for (int r = 0; r < 2; ++r)
      *(float4*)&sP[seg][rh * 2 + r][cg] = *(float4*)acc[r];
  }
  __syncthreads();
  {
    int r = t >> 7;
    float x = ws[WS_C0V + c0] + dem[row0 + r] * ws[WS_UV + c0];
#pragma unroll
    for (int sg = 0; sg < 8; ++sg) x += sP[sg][r][c0];
    outp[(size_t)(row0 + r) * 128 + c0] = x;
  }
}

extern "C" void kernel_launch(void* const* d_in, const int* in_sizes, int n_in,
                              void* d_out, int out_size, void* d_ws, size_t ws_size,
                              hipStream_t stream) {
  const float* cost   = (const float*)d_in[0];
  const float* dem    = (const float*)d_in[1];
  const float* rnd    = (const float*)d_in[2];
  // d_in[3] Wq, d_in[4] Wk unused (q == 0)
  const float* Wv     = (const float*)d_in[5];
  const float* mix1w  = (const float*)d_in[6];
  const float* mix1b  = (const float*)d_in[7];
  const float* mix2w  = (const float*)d_in[8];
  const float* mix2b  = (const float*)d_in[9];
  const float* Wo     = (const float*)d_in[10];
  const float* bo     = (const float*)d_in[11];
  const float* W1     = (const float*)d_in[12];
  const float* b1     = (const float*)d_in[13];
  const float* W2     = (const float*)d_in[14];
  const float* b2     = (const float*)d_in[15];
  const float* g1     = (const float*)d_in[16];
  const float* bb1    = (const float*)d_in[17];
  const float* g2     = (const float*)d_in[18];
  const float* bb2    = (const float*)d_in[19];
  const float* Wd     = (const float*)d_in[20];
  const float* bd     = (const float*)d_in[21];
  const float* Wn     = (const float*)d_in[22];
  const float* bnn    = (const float*)d_in[23];
  float* ws  = (float*)d_ws;
  float* out = (float*)d_out;

  hipLaunchKernelGGL(k_attn,  dim3(500), dim3(512), 0, stream, cost, rnd, Wv,
                     mix1w, mix1b, mix2w, mix2b, Wo, bo, ws);
  hipLaunchKernelGGL(k_red,   dim3(33),  dim3(256), 0, stream, Wn, Wd, bd, bnn,
                     ws, BN1P, 500, WS_SUM1);
  hipLaunchKernelGGL(k_ffn,   dim3(500), dim3(512), 0, stream, W1, b1, g1, bb1,
                     W2, b2, ws);
  hipLaunchKernelGGL(k_red,   dim3(32),  dim3(256), 0, stream, Wn, Wd, bd, bnn,
                     ws, BN2P, 500, WS_SUM2);
  hipLaunchKernelGGL(k_final, dim3(500), dim3(512), 0, stream, Wn, g2, bb2, dem,
                     out, ws);
}

// Round 19
// 47.986 us; speedup vs baseline: 4.6897x; 1.0554x over previous
//
#include <hip/hip_runtime.h>
#include <hip/hip_bf16.h>

// Node_EncodingBlock on MI355X. Inputs fp32, output fp32.
// R19 (final): exact resubmission of the best-measured config (R13, 48.1us).
// Structure: 5-kernel chain attn -> red1 -> ffn -> red2 -> final.
// The ~20us above component-sum (~27us) is per-launch-boundary fixed cost;
// all alternatives measured worse: coop grid.sync 177us, ticket+fence 225us,
// hipMemsetAsync +40us, per-block redundant reduce +10us/launch.

#define BN_EPS 1e-5f
// ws float offsets
#define WS_X1    256000     // [2000][128]
#define WS_X2    512000     // [2000][128]
#define WS_SUM1  768000
#define WS_SQ1   768128
#define WS_SUM2  768256
#define WS_SQ2   768384
#define WS_UV    768512
#define WS_C0V   768640
#define BN1P     770000     // [500][256]
#define BN2P     900000     // [500][256]

// 2-row GEMM micro-step (attn phase D / final)
#define GB8_R2(WPTR, LDW, KIDX, ACT2D, ACC)                             \
  {                                                                     \
    float4 w[8];                                                        \
    _Pragma("unroll")                                                   \
    for (int u = 0; u < 8; ++u)                                         \
      w[u] = *(const float4*)((WPTR) + (size_t)((KIDX) + u) * (LDW));   \
    _Pragma("unroll")                                                   \
    for (int u = 0; u < 8; ++u) {                                       \
      _Pragma("unroll")                                                 \
      for (int r = 0; r < 2; ++r) {                                     \
        float a = ACT2D[r][u];                                          \
        ACC[r][0] = fmaf(a, w[u].x, ACC[r][0]);                         \
        ACC[r][1] = fmaf(a, w[u].y, ACC[r][1]);                         \
        ACC[r][2] = fmaf(a, w[u].z, ACC[r][2]);                         \
        ACC[r][3] = fmaf(a, w[u].w, ACC[r][3]);                         \
      }                                                                 \
    }                                                                   \
  }

#define LD_AV2(SRC_ROW0, SRC_ROW1, KIDX, ACT2D)                         \
  {                                                                     \
    float4 x0 = *(const float4*)&(SRC_ROW0)[(KIDX)];                    \
    float4 y0 = *(const float4*)&(SRC_ROW0)[(KIDX) + 4];                \
    float4 x1 = *(const float4*)&(SRC_ROW1)[(KIDX)];                    \
    float4 y1 = *(const float4*)&(SRC_ROW1)[(KIDX) + 4];                \
    ACT2D[0][0]=x0.x; ACT2D[0][1]=x0.y; ACT2D[0][2]=x0.z; ACT2D[0][3]=x0.w; \
    ACT2D[0][4]=y0.x; ACT2D[0][5]=y0.y; ACT2D[0][6]=y0.z; ACT2D[0][7]=y0.w; \
    ACT2D[1][0]=x1.x; ACT2D[1][1]=x1.y; ACT2D[1][2]=x1.z; ACT2D[1][3]=x1.w; \
    ACT2D[1][4]=y1.x; ACT2D[1][5]=y1.y; ACT2D[1][6]=y1.z; ACT2D[1][7]=y1.w; \
  }

// 4-row x 4-col x 4-k batch: 4 independent float4 weight loads, 64 FMAs.
#define GB4_R4(WPTR, LDW, K0, SRC2D, ACC)                               \
  {                                                                     \
    float4 w[4];                                                        \
    _Pragma("unroll")                                                   \
    for (int u = 0; u < 4; ++u)                                         \
      w[u] = *(const float4*)((WPTR) + (size_t)((K0) + u) * (LDW));     \
    float av[4][4];                                                     \
    _Pragma("unroll")                                                   \
    for (int r = 0; r < 4; ++r) {                                       \
      float4 x = *(const float4*)&SRC2D[r][(K0)];                       \
      av[r][0] = x.x; av[r][1] = x.y; av[r][2] = x.z; av[r][3] = x.w;   \
    }                                                                   \
    _Pragma("unroll")                                                   \
    for (int u = 0; u < 4; ++u) {                                       \
      _Pragma("unroll")                                                 \
      for (int r = 0; r < 4; ++r) {                                     \
        ACC[r][0] = fmaf(av[r][u], w[u].x, ACC[r][0]);                  \
        ACC[r][1] = fmaf(av[r][u], w[u].y, ACC[r][1]);                  \
        ACC[r][2] = fmaf(av[r][u], w[u].z, ACC[r][2]);                  \
        ACC[r][3] = fmaf(av[r][u], w[u].w, ACC[r][3]);                  \
      }                                                                 \
    }                                                                   \
  }

// ---- kA: attention + multi_head_combine + BN1 partials --------------------
// 500 blocks x 512 thr, 4 rows/block.
__global__ __launch_bounds__(512, 6) void k_attn(const float* __restrict__ cost,
                                                 const float* __restrict__ rnd,
                                                 const float* __restrict__ Wv,
                                                 const float* __restrict__ mix1w,
                                                 const float* __restrict__ mix1b,
                                                 const float* __restrict__ mix2w,
                                                 const float* __restrict__ mix2b,
                                                 const float* __restrict__ Wo,
                                                 const float* __restrict__ bo,
                                                 float* __restrict__ ws) {
  __shared__ float pool[6152];   // [0:2056) traw | [2056:6152) lut ; C/D: sP[8][512]
  __shared__ float aw[32][132];
  __shared__ float soc[4][132];
  __shared__ float svr[128];
  __shared__ int   sperm[128];
  __shared__ float mu[8][16], mr[8][16], mA[8], mB[8];
  __shared__ float sS[512], sQ[512];
  const int t = threadIdx.x;
  const int lane = t & 63;
  const int blk = blockIdx.x;
  const int row0 = blk * 4;
  const int b = blk / 125;

  // early cost loads: wave (r, head-half) reads its row into registers.
  const int wr = (t >> 6) & 3;
  float cv8[8];
  {
    const float* crow = cost + (size_t)(row0 + wr) * 500;
#pragma unroll
    for (int ii = 0; ii < 8; ++ii) {
      int m = ii * 64 + lane;
      cv8[ii] = crow[m < 500 ? m : 499];
    }
  }
  if (t < 128) svr[t] = rnd[b * 128 + t];
  __syncthreads();
  if (t < 128) {
    float vt = svr[t];
    int rank = 0;
    for (int j = 0; j < 128; ++j) {
      float vj = svr[j];
      rank += (vj < vt) || (vj == vt && j < t);
    }
    sperm[rank] = t;
    // abs-form MLP params: g(c) = A c + B + sum u_s |c - r_s|
    int h = t >> 4, s = t & 15;
    float w1  = mix1w[h * 32 + 16 + s];
    float b1v = mix1b[h * 16 + s];
    float w2  = mix2w[h * 16 + s];
    bool tiny = fabsf(w1) < 1e-20f;
    float us = tiny ? 0.f : 0.5f * w2 * fabsf(w1);
    float rs = tiny ? 0.f : -b1v / w1;
    float Ap = 0.5f * w2 * w1;
    float Bp = 0.5f * w2 * b1v + (tiny ? 0.5f * w2 * fabsf(b1v) : 0.f);
    mu[h][s] = us; mr[h][s] = rs;
#pragma unroll
    for (int off = 1; off < 16; off <<= 1) {
      Ap += __shfl_xor(Ap, off);
      Bp += __shfl_xor(Bp, off);
    }
    if (s == 0) { mA[h] = Ap; mB[h] = Bp + mix2b[h]; }
  }
  __syncthreads();
  // LUT pass 1: traw[h][i] = exp(g_h(i/255))
  float* traw = pool;
  float2* lut = (float2*)(pool + 2056);
  if (t < 257) {
    float x = (float)t * (1.f / 255.f);
    for (int h = 0; h < 8; ++h) {
      float g = fmaf(x, mA[h], mB[h]);
#pragma unroll
      for (int s = 0; s < 16; ++s)
        g = fmaf(fabsf(x - mr[h][s]), mu[h][s], g);
      traw[h * 257 + t] = __expf(g);
    }
  }
  __syncthreads();
#pragma unroll
  for (int p = 0; p < 4; ++p) {
    int e = t + p * 512;
    int h = e >> 8, i = e & 255;
    float a = traw[h * 257 + i];
    lut[e] = float2{a, traw[h * 257 + i + 1] - a};
  }
  __syncthreads();
  // phase B: wave (wr, head-half): LUT scores -> aggregated softmax weights
  {
    const int h0 = ((t >> 6) >> 2) * 4;
    for (int h = h0; h < h0 + 4; ++h) {
      const float2* lh = &lut[h * 256];
      float wsum = 0.f, a0 = 0.f, a1 = 0.f;
#pragma unroll
      for (int ii = 0; ii < 8; ++ii) {
        float u = cv8[ii] * 255.f;
        int i = (int)u;
        float f = u - (float)i;
        float2 td = lh[i];
        float e = fmaf(td.y, f, td.x);
        if (ii == 7 && lane >= 52) e = 0.f;   // mask m >= 500
        wsum += e;
        if (ii & 1) a1 += e; else a0 += e;
      }
#pragma unroll
      for (int off = 32; off; off >>= 1) wsum += __shfl_xor(wsum, off);
      float inv = 1.f / wsum;
      aw[wr * 8 + h][lane]      = a0 * inv;
      aw[wr * 8 + h][64 + lane] = a1 * inv;
    }
  }
  __syncthreads();
  // phase C: oc[r][c] = sum_j aw[r*8+(c>>4)][j] * Wv[perm[j]][c]; j-split 4
  float* sP = pool;                    // [8][512] view; lut dead from here
  {
    const int c  = t & 127;
    const int jh = t >> 7;
    const int h  = c >> 4;
    float acc4[4] = {0.f, 0.f, 0.f, 0.f};
    for (int jb = jh * 32; jb < jh * 32 + 32; jb += 8) {
      int rows[8];
#pragma unroll
      for (int u = 0; u < 8; ++u) rows[u] = sperm[jb + u];
      float wv8[8];
#pragma unroll
      for (int u = 0; u < 8; ++u) wv8[u] = Wv[(size_t)rows[u] * 128 + c];
#pragma unroll
      for (int r = 0; r < 4; ++r) {
        float4 aa = *(const float4*)&aw[r * 8 + h][jb];
        float4 ab = *(const float4*)&aw[r * 8 + h][jb + 4];
        acc4[r] = fmaf(aa.x, wv8[0], acc4[r]);
        acc4[r] = fmaf(aa.y, wv8[1], acc4[r]);
        acc4[r] = fmaf(aa.z, wv8[2], acc4[r]);
        acc4[r] = fmaf(aa.w, wv8[3], acc4[r]);
        acc4[r] = fmaf(ab.x, wv8[4], acc4[r]);
        acc4[r] = fmaf(ab.y, wv8[5], acc4[r]);
        acc4[r] = fmaf(ab.z, wv8[6], acc4[r]);
        acc4[r] = fmaf(ab.w, wv8[7], acc4[r]);
      }
    }
#pragma unroll
    for (int r = 0; r < 4; ++r) sP[(size_t)jh * 512 + r * 128 + c] = acc4[r];
  }
  __syncthreads();
  {
    int r = t >> 7, c = t & 127;
    soc[r][c] = sP[r * 128 + c] + sP[512 + r * 128 + c] +
                sP[1024 + r * 128 + c] + sP[1536 + r * 128 + c];
  }
  __syncthreads();
  // phase D: X1 = soc @ Wo + bo; k-split 8 x row-half 2
  {
    const int cg  = (t & 31) * 4;
    const int seg = (t >> 5) & 7;
    const int rh  = t >> 8;
    const int k0  = seg * 16;
    float acc[2][4] = {};
    float av[2][8];
#pragma unroll
    for (int kb = 0; kb < 16; kb += 8) {
      LD_AV2(soc[rh * 2], soc[rh * 2 + 1], k0 + kb, av);
      GB8_R2(Wo + cg, 128, k0 + kb, av, acc);
    }
#pragma unroll
    for (int r = 0; r < 2; ++r)
      *(float4*)&sP[(size_t)seg * 512 + (rh * 2 + r) * 128 + cg] = *(float4*)acc[r];
  }
  __syncthreads();
  {
    int r = t >> 7, col = t & 127;
    float x = bo[col];
#pragma unroll
    for (int sg = 0; sg < 8; ++sg) x += sP[(size_t)sg * 512 + r * 128 + col];
    ws[WS_X1 + (size_t)(row0 + r) * 128 + col] = x;
    sS[t] = x; sQ[t] = x * x;
  }
  __syncthreads();
  if (t < 128) {
    ws[BN1P + blk * 256 + t]       = sS[t] + sS[t+128] + sS[t+256] + sS[t+384];
    ws[BN1P + blk * 256 + 128 + t] = sQ[t] + sQ[t+128] + sQ[t+256] + sQ[t+384];
  }
}

// ---- k_red: 32 blocks reduce partials; block 32 (if present): U/C0 --------
__global__ __launch_bounds__(256) void k_red(const float* __restrict__ Wn,
                                             const float* __restrict__ Wd,
                                             const float* __restrict__ bd,
                                             const float* __restrict__ bnn,
                                             float* __restrict__ ws,
                                             int src, int nslots, int dst) {
  const int t = threadIdx.x;
  if (blockIdx.x < 32) {
    __shared__ float red[32][9];
    const int col = blockIdx.x * 8 + (t & 7);
    const int strip = t >> 3;          // 0..31
    float s = 0.f;
    for (int j = strip; j < nslots; j += 32) s += ws[src + j * 256 + col];
    red[strip][t & 7] = s;
    __syncthreads();
    if (t < 8) {
      float x = 0.f;
#pragma unroll
      for (int k = 0; k < 32; ++k) x += red[k][t];
      ws[dst + blockIdx.x * 8 + t] = x;
    }
  } else {
    __shared__ float ru[2][128], rc[2][128];
    const int c = t & 127, g = t >> 7;
    float u = 0.f, cc = 0.f;
#pragma unroll 8
    for (int e = g * 64; e < g * 64 + 64; ++e) {
      float wn = Wn[(size_t)(128 + e) * 128 + c];
      u  = fmaf(Wd[e], wn, u);
      cc = fmaf(bd[e], wn, cc);
    }
    ru[g][c] = u; rc[g][c] = cc;
    __syncthreads();
    if (t < 128) {
      ws[WS_UV + t]  = ru[0][t] + ru[1][t];
      ws[WS_C0V + t] = rc[0][t] + rc[1][t] + bnn[t];
    }
  }
}

// ---- kB: BN1 -> FFN -> X2 + BN2 partials ----------------------------------
// 500 blocks x 512 thr, 4 rows/block. Weights once/block; ~43KB LDS.
__global__ __launch_bounds__(512, 2) void k_ffn(const float* __restrict__ W1,
                                                const float* __restrict__ b1,
                                                const float* __restrict__ g1,
                                                const float* __restrict__ bb1,
                                                const float* __restrict__ W2,
                                                const float* __restrict__ b2,
                                                float* __restrict__ ws) {
  __shared__ float o1[4][128];
  __shared__ float sY[4][512];
  __shared__ float sP[4][4][512];      // 32 KB; GEMM2 view [16][4][128]
  __shared__ float sS[512], sQ[512];
  const int t = threadIdx.x;
  const int blk = blockIdx.x;
  const int row0 = blk * 4;
  const int c0 = t & 127;
  float m1 = ws[WS_SUM1 + c0] * 5e-4f;
  float v1 = ws[WS_SQ1 + c0] * 5e-4f - m1 * m1;
  float scv = g1[c0] * rsqrtf(v1 + BN_EPS);
  float shv = bb1[c0] - m1 * scv;
  {
    int r = t >> 7;
    o1[r][c0] = ws[WS_X1 + (size_t)(row0 + r) * 128 + c0] * scv + shv;
  }
  __syncthreads();
  // GEMM1 (128->512): cg(128 x 4cols) x kseg(4 x 32k), 4-row accumulate
  {
    const int cg   = (t & 127) * 4;
    const int kseg = t >> 7;
    const int kb0  = kseg * 32;
    float acc[4][4] = {};
#pragma unroll
    for (int kb = 0; kb < 32; kb += 4)
      GB4_R4(W1 + cg, 512, kb0 + kb, o1, acc);
#pragma unroll
    for (int r = 0; r < 4; ++r)
      *(float4*)&sP[kseg][r][cg] = *(float4*)acc[r];
  }
  __syncthreads();
#pragma unroll
  for (int i = 0; i < 4; ++i) {
    int idx = t + i * 512;
    int r = idx >> 9, c = idx & 511;
    float x = sP[0][r][c] + sP[1][r][c] + sP[2][r][c] + sP[3][r][c];
    sY[r][c] = fmaxf(x + b1[c], 0.f);
  }
  __syncthreads();
  // GEMM2 (512->128): cg(32 x 4cols) x kseg(16 x 32k), 4-row accumulate
  float* p2 = &sP[0][0][0];            // [16][4][128] view
  {
    const int cg   = (t & 31) * 4;
    const int kseg = t >> 5;
    const int kb0  = kseg * 32;
    float acc[4][4] = {};
#pragma unroll
    for (int kb = 0; kb < 32; kb += 4)
      GB4_R4(W2 + cg, 128, kb0 + kb, sY, acc);
#pragma unroll
    for (int r = 0; r < 4; ++r)
      *(float4*)(p2 + (size_t)(kseg * 4 + r) * 128 + cg) = *(float4*)acc[r];
  }
  __syncthreads();
  {
    int r = t >> 7, c = t & 127;
    float x = b2[c] + o1[r][c];
#pragma unroll
    for (int sg = 0; sg < 16; ++sg) x += p2[(size_t)(sg * 4 + r) * 128 + c];
    ws[WS_X2 + (size_t)(row0 + r) * 128 + c] = x;
    sS[t] = x; sQ[t] = x * x;
  }
  __syncthreads();
  if (t < 128) {
    ws[BN2P + blk * 256 + t]       = sS[t] + sS[t+128] + sS[t+256] + sS[t+384];
    ws[BN2P + blk * 256 + 128 + t] = sQ[t] + sQ[t+128] + sQ[t+256] + sQ[t+384];
  }
}

// ---- kC: BN2 -> out3 @ Wn_top + demand*U + C0 -> out ----------------------
__global__ __launch_bounds__(512, 4) void k_final(const float* __restrict__ Wn,
                                                  const float* __restrict__ g2,
                                                  const float* __restrict__ bb2,
                                                  const float* __restrict__ dem,
                                                  float* __restrict__ outp,
                                                  float* __restrict__ ws) {
  __shared__ float o3[4][132];
  __shared__ float sP[8][4][128];
  const int t = threadIdx.x;
  const int blk = blockIdx.x;
  const int row0 = blk * 4;
  const int c0 = t & 127;
  float m2 = ws[WS_SUM2 + c0] * 5e-4f;
  float v2 = ws[WS_SQ2 + c0] * 5e-4f - m2 * m2;
  float scv = g2[c0] * rsqrtf(v2 + BN_EPS);
  float shv = bb2[c0] - m2 * scv;
  {
    int r = t >> 7;
    o3[r][c0] = ws[WS_X2 + (size_t)(row0 + r) * 128 + c0] * scv + shv;
  }
  __syncthreads();
  {
    const int cg  = (t & 31) * 4;
    const int seg = (t >> 5) & 7;
    const int rh  = t >> 8;
    const int k0  = seg * 16;
    float acc[2][4] = {};
    float av[2][8];
#pragma unroll
    for (int kb = 0; kb < 16; kb += 8) {
      LD_AV2(o3[rh * 2], o3[rh * 2 + 1], k0 + kb, av);
      GB8_R2(Wn + cg, 128, k0 + kb, av, acc);
    }
#pragma unroll
    for (int r = 0; r < 2; ++r)
      *(float4*)&sP[seg][rh * 2 + r][cg] = *(float4*)acc[r];
  }
  __syncthreads();
  {
    int r = t >> 7;
    float x = ws[WS_C0V + c0] + dem[row0 + r] * ws[WS_UV + c0];
#pragma unroll
    for (int sg = 0; sg < 8; ++sg) x += sP[sg][r][c0];
    outp[(size_t)(row0 + r) * 128 + c0] = x;
  }
}

extern "C" void kernel_launch(void* const* d_in, const int* in_sizes, int n_in,
                              void* d_out, int out_size, void* d_ws, size_t ws_size,
                              hipStream_t stream) {
  const float* cost   = (const float*)d_in[0];
  const float* dem    = (const float*)d_in[1];
  const float* rnd    = (const float*)d_in[2];
  // d_in[3] Wq, d_in[4] Wk unused (q == 0)
  const float* Wv     = (const float*)d_in[5];
  const float* mix1w  = (const float*)d_in[6];
  const float* mix1b  = (const float*)d_in[7];
  const float* mix2w  = (const float*)d_in[8];
  const float* mix2b  = (const float*)d_in[9];
  const float* Wo     = (const float*)d_in[10];
  const float* bo     = (const float*)d_in[11];
  const float* W1     = (const float*)d_in[12];
  const float* b1     = (const float*)d_in[13];
  const float* W2     = (const float*)d_in[14];
  const float* b2     = (const float*)d_in[15];
  const float* g1     = (const float*)d_in[16];
  const float* bb1    = (const float*)d_in[17];
  const float* g2     = (const float*)d_in[18];
  const float* bb2    = (const float*)d_in[19];
  const float* Wd     = (const float*)d_in[20];
  const float* bd     = (const float*)d_in[21];
  const float* Wn     = (const float*)d_in[22];
  const float* bnn    = (const float*)d_in[23];
  float* ws  = (float*)d_ws;
  float* out = (float*)d_out;

  hipLaunchKernelGGL(k_attn,  dim3(500), dim3(512), 0, stream, cost, rnd, Wv,
                     mix1w, mix1b, mix2w, mix2b, Wo, bo, ws);
  hipLaunchKernelGGL(k_red,   dim3(33),  dim3(256), 0, stream, Wn, Wd, bd, bnn,
                     ws, BN1P, 500, WS_SUM1);
  hipLaunchKernelGGL(k_ffn,   dim3(500), dim3(512), 0, stream, W1, b1, g1, bb1,
                     W2, b2, ws);
  hipLaunchKernelGGL(k_red,   dim3(32),  dim3(256), 0, stream, Wn, Wd, bd, bnn,
                     ws, BN2P, 500, WS_SUM2);
  hipLaunchKernelGGL(k_final, dim3(500), dim3(512), 0, stream, Wn, g2, bb2, dem,
                     out, ws);
}